// Round 1
// baseline (6978.545 us; speedup 1.0000x reference)
//
#include <hip/hip_runtime.h>
#include <hip/hip_bf16.h>

typedef float f32x4 __attribute__((ext_vector_type(4)));
typedef __bf16 bf16x8 __attribute__((ext_vector_type(8)));
typedef unsigned short u16x8 __attribute__((ext_vector_type(8)));

#define NTOK 197
#define MTOT (64 * 197)   /* 12608 */
#define MPAD 12672        /* 99 * 128 */
#define CDIM 768
#define FDIM 3072
#define NPAD 224

__device__ __forceinline__ unsigned short f2b(float f) {
  unsigned u = __builtin_bit_cast(unsigned, f);
  u += 0x7fffu + ((u >> 16) & 1u);
  return (unsigned short)(u >> 16);
}

__device__ __forceinline__ bf16x8 ldfrag(const unsigned short* p) {
  return __builtin_bit_cast(bf16x8, *(const u16x8*)p);
}

__device__ __forceinline__ f32x4 mfma16(bf16x8 a, bf16x8 b, f32x4 c) {
  return __builtin_amdgcn_mfma_f32_16x16x32_bf16(a, b, c, 0, 0, 0);
}

__device__ __forceinline__ void gload_lds16(const void* g, void* l) {
  __builtin_amdgcn_global_load_lds((const __attribute__((address_space(1))) void*)g,
                                   (__attribute__((address_space(3))) void*)l, 16, 0, 0);
}

// ---------------- embed: h = concat(cls, x) + sinusoidal PE ----------------
__global__ void embed_kernel(const float* __restrict__ x, const float* __restrict__ cls,
                             float* __restrict__ h) {
  const long i = (long)blockIdx.x * 256 + threadIdx.x;  // 64*197*768 total, exact grid
  const int c = (int)(i % CDIM);
  const long bn = i / CDIM;
  const int n = (int)(bn % NTOK);
  const int b = (int)(bn / NTOK);
  const float val = (n == 0) ? cls[c] : x[((size_t)b * 196 + (n - 1)) * CDIM + c];
  // freq = exp(-ln(10000) * 2*(c/2) / 768)
  const float freq = expf(-0.02398526138f * (float)(c >> 1));
  const float ang = (float)n * freq;
  const float pe = (c & 1) ? cosf(ang) : sinf(ang);
  h[i] = val + pe;
}

// ---------------- fp32 -> bf16 weight conversion (4 regions) ----------------
__global__ void convert4(const float* __restrict__ s0, int n0,
                         const float* __restrict__ s1, int n1,
                         const float* __restrict__ s2, int n2,
                         const float* __restrict__ s3, int n3,
                         unsigned short* __restrict__ dst) {
  const long j = ((long)blockIdx.x * 256 + threadIdx.x) * 4;
  const float* s;
  long o = j;
  if (o < n0) s = s0;
  else { o -= n0;
    if (o < n1) s = s1;
    else { o -= n1;
      if (o < n2) s = s2;
      else { o -= n2; s = s3; } } }
  const float4 v = *(const float4*)(s + o);
  *(ushort4*)(dst + j) = make_ushort4(f2b(v.x), f2b(v.y), f2b(v.z), f2b(v.w));
}

// ---------------- LayerNorm (one block of 256 per row, 768 cols) ------------
__global__ __launch_bounds__(256)
void ln_kernel(const float* __restrict__ x, long rstride,
               const float* __restrict__ w, const float* __restrict__ bvec,
               unsigned short* __restrict__ y) {
  const int row = blockIdx.x, tid = threadIdx.x;
  const float* xr = x + (size_t)row * rstride;
  const float v0 = xr[tid], v1 = xr[tid + 256], v2 = xr[tid + 512];
  float s = v0 + v1 + v2;
  float ss = v0 * v0 + v1 * v1 + v2 * v2;
#pragma unroll
  for (int off = 32; off >= 1; off >>= 1) {
    s += __shfl_xor(s, off);
    ss += __shfl_xor(ss, off);
  }
  __shared__ float sm[8];
  const int wv = tid >> 6;
  if ((tid & 63) == 0) { sm[wv] = s; sm[wv + 4] = ss; }
  __syncthreads();
  s = sm[0] + sm[1] + sm[2] + sm[3];
  ss = sm[4] + sm[5] + sm[6] + sm[7];
  const float mu = s * (1.0f / 768.0f);
  const float var = ss * (1.0f / 768.0f) - mu * mu;
  const float rstd = rsqrtf(var + 1e-5f);
  unsigned short* yr = y + (size_t)row * CDIM;
  yr[tid]       = f2b((v0 - mu) * rstd * w[tid]       + bvec[tid]);
  yr[tid + 256] = f2b((v1 - mu) * rstd * w[tid + 256] + bvec[tid + 256]);
  yr[tid + 512] = f2b((v2 - mu) * rstd * w[tid + 512] + bvec[tid + 512]);
}

// ---------------- GEMM: C = A(M x K) * B^T(N x K), m97 128^2 structure ------
enum { EPI_QKV = 0, EPI_RES = 1, EPI_GELU = 2 };

template <int EPI>
__global__ __launch_bounds__(256)
void gemm_bt(const unsigned short* __restrict__ A, const unsigned short* __restrict__ B,
             int K,
             float* __restrict__ hres, const float* __restrict__ bias,
             unsigned short* __restrict__ obf,
             unsigned short* __restrict__ qb, unsigned short* __restrict__ kbuf,
             unsigned short* __restrict__ vb) {
  __shared__ unsigned short As[128 * 64];
  __shared__ unsigned short Bs[128 * 64];
  const int tid = threadIdx.x;
  const int lane = tid & 63, wv = tid >> 6;
  const int wm = wv >> 1, wn = wv & 1;
  const int ll = lane & 15, lg = lane >> 4;
  const int m0 = blockIdx.y * 128, n0 = blockIdx.x * 128;

  const f32x4 zero = {0.f, 0.f, 0.f, 0.f};
  f32x4 acc[4][4];
#pragma unroll
  for (int i = 0; i < 4; i++)
#pragma unroll
    for (int j = 0; j < 4; j++) acc[i][j] = zero;

  const unsigned short* Ag = A + (size_t)m0 * K;
  const unsigned short* Bg = B + (size_t)n0 * K;

  for (int k0 = 0; k0 < K; k0 += 64) {
    __syncthreads();
#pragma unroll
    for (int i = 0; i < 4; i++) {
      const int cb = ((i << 2) + wv) << 10;  // 1KB chunk base in LDS
      const int ob = cb + (lane << 4);
      const int row = ob >> 7, kel = (ob & 127) >> 1;
      gload_lds16(Ag + (size_t)row * K + k0 + kel, (char*)As + cb);
      gload_lds16(Bg + (size_t)row * K + k0 + kel, (char*)Bs + cb);
    }
    __syncthreads();
#pragma unroll
    for (int kk = 0; kk < 64; kk += 32) {
      bf16x8 af[4], bfv[4];
#pragma unroll
      for (int i = 0; i < 4; i++)
        af[i] = ldfrag(&As[(wm * 64 + i * 16 + ll) * 64 + kk + (lg << 3)]);
#pragma unroll
      for (int j = 0; j < 4; j++)
        bfv[j] = ldfrag(&Bs[(wn * 64 + j * 16 + ll) * 64 + kk + (lg << 3)]);
#pragma unroll
      for (int i = 0; i < 4; i++)
#pragma unroll
        for (int j = 0; j < 4; j++)
          acc[i][j] = mfma16(af[i], bfv[j], acc[i][j]);
    }
  }

#pragma unroll
  for (int i = 0; i < 4; i++) {
#pragma unroll
    for (int r = 0; r < 4; r++) {
      const int m = m0 + wm * 64 + i * 16 + lg * 4 + r;
      if (m >= MTOT) continue;
      if constexpr (EPI == EPI_QKV) {
        const int b = m / 197, n = m - b * 197;
#pragma unroll
        for (int j = 0; j < 4; j++) {
          const int e = n0 + wn * 64 + j * 16 + ll;
          const float v = acc[i][j][r];
          const int t = e / 768, rem = e - t * 768;
          const int hh = rem >> 6, d = rem & 63;
          if (t == 0)
            qb[((size_t)(b * 12 + hh) * NPAD + n) * 64 + d] = f2b(v * 0.125f);
          else if (t == 1)
            kbuf[((size_t)(b * 12 + hh) * NPAD + n) * 64 + d] = f2b(v);
          else
            vb[((size_t)(b * 12 + hh) * 64 + d) * NPAD + n] = f2b(v);  // V^T
        }
      } else if constexpr (EPI == EPI_RES) {
#pragma unroll
        for (int j = 0; j < 4; j++) {
          const int c = n0 + wn * 64 + j * 16 + ll;
          const size_t idx = (size_t)m * CDIM + c;
          hres[idx] += acc[i][j][r] + bias[c];
        }
      } else {  // EPI_GELU -> bf16 store, width 3072
#pragma unroll
        for (int j = 0; j < 4; j++) {
          const int c = n0 + wn * 64 + j * 16 + ll;
          const float t = acc[i][j][r] + bias[c];
          const float g = 0.5f * t * (1.0f + erff(t * 0.7071067811865475f));
          obf[(size_t)m * FDIM + c] = f2b(g);
        }
      }
    }
  }
}

// ---------------- attention: 1 wave per (b,h,qtile of 16 rows) --------------
__global__ __launch_bounds__(64)
void attn_kernel(const unsigned short* __restrict__ qb, const unsigned short* __restrict__ kbuf,
                 const unsigned short* __restrict__ vb, unsigned short* __restrict__ o) {
  __shared__ unsigned short P[16 * 232];  // padded rows: 232*2B -> conflict-friendly
  const int lane = threadIdx.x, ll = lane & 15, lg = lane >> 4;
  const int qt = blockIdx.x, bh = blockIdx.y;
  const int b = bh / 12, hh = bh - b * 12;
  const size_t base = (size_t)bh * NPAD * 64;
  const unsigned short* Q = qb + base + (size_t)qt * 16 * 64;
  const unsigned short* Kp = kbuf + base;
  const unsigned short* Vt = vb + base;  // [64][224]

  const bf16x8 qf0 = ldfrag(&Q[ll * 64 + (lg << 3)]);
  const bf16x8 qf1 = ldfrag(&Q[ll * 64 + 32 + (lg << 3)]);

  const f32x4 zero = {0.f, 0.f, 0.f, 0.f};
  f32x4 s[14];
#pragma unroll
  for (int kt = 0; kt < 14; kt++) {
    f32x4 a = zero;
    a = mfma16(qf0, ldfrag(&Kp[(kt * 16 + ll) * 64 + (lg << 3)]), a);
    a = mfma16(qf1, ldfrag(&Kp[(kt * 16 + ll) * 64 + 32 + (lg << 3)]), a);
    s[kt] = a;
  }
  float mx[4] = {-1e30f, -1e30f, -1e30f, -1e30f};
#pragma unroll
  for (int kt = 0; kt < 14; kt++) {
    const bool ok = (kt * 16 + ll) < NTOK;
#pragma unroll
    for (int r = 0; r < 4; r++) {
      const float v = ok ? s[kt][r] : -1e30f;
      s[kt][r] = v;
      mx[r] = fmaxf(mx[r], v);
    }
  }
#pragma unroll
  for (int off = 1; off < 16; off <<= 1)
#pragma unroll
    for (int r = 0; r < 4; r++) mx[r] = fmaxf(mx[r], __shfl_xor(mx[r], off));

  float sum[4] = {0.f, 0.f, 0.f, 0.f};
#pragma unroll
  for (int kt = 0; kt < 14; kt++)
#pragma unroll
    for (int r = 0; r < 4; r++) {
      const float p = __expf(s[kt][r] - mx[r]);
      sum[r] += p;
      P[(lg * 4 + r) * 232 + kt * 16 + ll] = f2b(p);
    }
#pragma unroll
  for (int off = 1; off < 16; off <<= 1)
#pragma unroll
    for (int r = 0; r < 4; r++) sum[r] += __shfl_xor(sum[r], off);

  __syncthreads();  // order P writes vs cross-lane P reads (1 wave, cheap)

  f32x4 oa[4] = {zero, zero, zero, zero};
#pragma unroll
  for (int ks = 0; ks < 7; ks++) {
    const bf16x8 pf = ldfrag(&P[ll * 232 + ks * 32 + (lg << 3)]);
#pragma unroll
    for (int dt = 0; dt < 4; dt++) {
      const bf16x8 vf = ldfrag(&Vt[(dt * 16 + ll) * NPAD + ks * 32 + (lg << 3)]);
      oa[dt] = mfma16(pf, vf, oa[dt]);
    }
  }
#pragma unroll
  for (int r = 0; r < 4; r++) {
    const int n = qt * 16 + lg * 4 + r;
    if (n < NTOK) {
      const float rc = 1.0f / sum[r];
      unsigned short* orow = o + ((size_t)(b * 197 + n)) * CDIM + hh * 64;
#pragma unroll
      for (int dt = 0; dt < 4; dt++) orow[dt * 16 + ll] = f2b(oa[dt][r] * rc);
    }
  }
}

// ---------------- head: cls(64x768) @ head_w^T(1000x768) + b ----------------
__global__ __launch_bounds__(64)
void head_kernel(const unsigned short* __restrict__ clsb, const unsigned short* __restrict__ hw,
                 const float* __restrict__ hb, float* __restrict__ out) {
  const int lane = threadIdx.x, ll = lane & 15, lg = lane >> 4;
  const int nt = blockIdx.x, mt = blockIdx.y;
  f32x4 acc = {0.f, 0.f, 0.f, 0.f};
  const int nrow = min(nt * 16 + ll, 999);
#pragma unroll 4
  for (int k0 = 0; k0 < 768; k0 += 32) {
    const bf16x8 a = ldfrag(&clsb[(mt * 16 + ll) * 768 + k0 + (lg << 3)]);
    const bf16x8 b = ldfrag(&hw[(size_t)nrow * 768 + k0 + (lg << 3)]);
    acc = mfma16(a, b, acc);
  }
  const int col = nt * 16 + ll;
#pragma unroll
  for (int r = 0; r < 4; r++) {
    const int row = mt * 16 + lg * 4 + r;
    if (col < 1000) out[row * 1000 + col] = acc[r] + hb[col];
  }
}

// ---------------- workspace layout ----------------
static constexpr size_t SZ_H  = (size_t)MPAD * CDIM * 4;
static constexpr size_t SZ_Y  = (size_t)MPAD * CDIM * 2;
static constexpr size_t SZ_O  = SZ_Y;
static constexpr size_t SZ_MM = (size_t)MPAD * FDIM * 2;
static constexpr size_t SZ_Q1 = (size_t)64 * 12 * NPAD * 64 * 2;  // 22,020,096
static constexpr size_t SZ_WB = (size_t)(2304 * 768 + 768 * 768 + 3072 * 768 + 768 * 3072) * 2;
static constexpr size_t OFF_H  = 0;
static constexpr size_t OFF_Y  = OFF_H + SZ_H;
static constexpr size_t OFF_O  = OFF_Y + SZ_Y;
static constexpr size_t OFF_MM = OFF_O + SZ_O;
static constexpr size_t OFF_Q  = OFF_MM + SZ_MM;
static constexpr size_t OFF_K  = OFF_Q + SZ_Q1;
static constexpr size_t OFF_V  = OFF_K + SZ_Q1;
static constexpr size_t OFF_WB = OFF_V + SZ_Q1;
static constexpr size_t OFF_WH = OFF_WB + SZ_WB;
static constexpr size_t OFF_CLS = OFF_WH + (size_t)1000 * 768 * 2;

extern "C" void kernel_launch(void* const* d_in, const int* in_sizes, int n_in,
                              void* d_out, int out_size, void* d_ws, size_t ws_size,
                              hipStream_t stream) {
  const float* x      = (const float*)d_in[0];
  const float* cls    = (const float*)d_in[1];
  const float* qkv_w  = (const float*)d_in[2];
  const float* proj_w = (const float*)d_in[3];
  const float* proj_b = (const float*)d_in[4];
  const float* ln1_w  = (const float*)d_in[5];
  const float* ln1_b  = (const float*)d_in[6];
  const float* ln2_w  = (const float*)d_in[7];
  const float* ln2_b  = (const float*)d_in[8];
  const float* fc1_w  = (const float*)d_in[9];
  const float* fc1_b  = (const float*)d_in[10];
  const float* fc2_w  = (const float*)d_in[11];
  const float* fc2_b  = (const float*)d_in[12];
  const float* norm_w = (const float*)d_in[13];
  const float* norm_b = (const float*)d_in[14];
  const float* head_w = (const float*)d_in[15];
  const float* head_b = (const float*)d_in[16];
  float* out = (float*)d_out;

  char* ws = (char*)d_ws;
  float*          h    = (float*)(ws + OFF_H);
  unsigned short* ybf  = (unsigned short*)(ws + OFF_Y);
  unsigned short* obf  = (unsigned short*)(ws + OFF_O);
  unsigned short* mmbf = (unsigned short*)(ws + OFF_MM);
  unsigned short* qbuf = (unsigned short*)(ws + OFF_Q);
  unsigned short* kbuf = (unsigned short*)(ws + OFF_K);
  unsigned short* vbuf = (unsigned short*)(ws + OFF_V);
  unsigned short* wbuf = (unsigned short*)(ws + OFF_WB);
  unsigned short* whd  = (unsigned short*)(ws + OFF_WH);
  unsigned short* clsb = (unsigned short*)(ws + OFF_CLS);

  unsigned short* wqkv = wbuf;
  unsigned short* wprj = wqkv + 2304 * 768;
  unsigned short* wfc1 = wprj + 768 * 768;
  unsigned short* wfc2 = wfc1 + 3072 * 768;

  // zero q/k/v padding once per call (ws is re-poisoned before every call)
  hipMemsetAsync(ws + OFF_Q, 0, 3 * SZ_Q1, stream);

  embed_kernel<<<37824, 256, 0, stream>>>(x, cls, h);
  convert4<<<750, 256, 0, stream>>>(head_w, 768000, head_w, 0, head_w, 0, head_w, 0, whd);

  for (int d = 0; d < 12; ++d) {
    convert4<<<6912, 256, 0, stream>>>(qkv_w + (size_t)d * 2304 * 768, 2304 * 768,
                                       proj_w + (size_t)d * 768 * 768, 768 * 768,
                                       fc1_w + (size_t)d * 3072 * 768, 3072 * 768,
                                       fc2_w + (size_t)d * 768 * 3072, 768 * 3072, wbuf);
    ln_kernel<<<MTOT, 256, 0, stream>>>(h, CDIM, ln1_w + d * 768, ln1_b + d * 768, ybf);
    gemm_bt<EPI_QKV><<<dim3(18, 99), 256, 0, stream>>>(ybf, wqkv, 768, nullptr, nullptr,
                                                       nullptr, qbuf, kbuf, vbuf);
    attn_kernel<<<dim3(13, 768), 64, 0, stream>>>(qbuf, kbuf, vbuf, obf);
    gemm_bt<EPI_RES><<<dim3(6, 99), 256, 0, stream>>>(obf, wprj, 768, h, proj_b + d * 768,
                                                      nullptr, nullptr, nullptr, nullptr);
    ln_kernel<<<MTOT, 256, 0, stream>>>(h, CDIM, ln2_w + d * 768, ln2_b + d * 768, ybf);
    gemm_bt<EPI_GELU><<<dim3(24, 99), 256, 0, stream>>>(ybf, wfc1, 768, nullptr,
                                                        fc1_b + d * 3072, mmbf, nullptr,
                                                        nullptr, nullptr);
    gemm_bt<EPI_RES><<<dim3(6, 99), 256, 0, stream>>>(mmbf, wfc2, 3072, h, fc2_b + d * 768,
                                                      nullptr, nullptr, nullptr, nullptr);
  }
  ln_kernel<<<64, 256, 0, stream>>>(h, (long)197 * 768, norm_w, norm_b, clsb);
  head_kernel<<<dim3(63, 4), 64, 0, stream>>>(clsb, whd, head_b, out);
}

// Round 3
// 5848.352 us; speedup vs baseline: 1.1932x; 1.1932x over previous
//
#include <hip/hip_runtime.h>
#include <hip/hip_bf16.h>

typedef float f32x4 __attribute__((ext_vector_type(4)));
typedef __bf16 bf16x8 __attribute__((ext_vector_type(8)));
typedef unsigned short u16x8 __attribute__((ext_vector_type(8)));

#define NTOK 197
#define MTOT (64 * 197)   /* 12608 */
#define MPAD 12800        /* 50 * 256 */
#define CDIM 768
#define FDIM 3072
#define NPAD 224

__device__ __forceinline__ unsigned short f2b(float f) {
  unsigned u = __builtin_bit_cast(unsigned, f);
  u += 0x7fffu + ((u >> 16) & 1u);
  return (unsigned short)(u >> 16);
}

__device__ __forceinline__ bf16x8 ldfrag(const unsigned short* p) {
  return __builtin_bit_cast(bf16x8, *(const u16x8*)p);
}

__device__ __forceinline__ f32x4 mfma16(bf16x8 a, bf16x8 b, f32x4 c) {
  return __builtin_amdgcn_mfma_f32_16x16x32_bf16(a, b, c, 0, 0, 0);
}

__device__ __forceinline__ void gload_lds16(const void* g, void* l) {
  __builtin_amdgcn_global_load_lds((const __attribute__((address_space(1))) void*)g,
                                   (__attribute__((address_space(3))) void*)l, 16, 0, 0);
}

// ---------------- embed: h = concat(cls, x) + sinusoidal PE ----------------
__global__ void embed_kernel(const float* __restrict__ x, const float* __restrict__ cls,
                             float* __restrict__ h) {
  const long i = (long)blockIdx.x * 256 + threadIdx.x;  // 64*197*768 total, exact grid
  const int c = (int)(i % CDIM);
  const long bn = i / CDIM;
  const int n = (int)(bn % NTOK);
  const int b = (int)(bn / NTOK);
  const float val = (n == 0) ? cls[c] : x[((size_t)b * 196 + (n - 1)) * CDIM + c];
  const float freq = expf(-0.02398526138f * (float)(c >> 1));
  const float ang = (float)n * freq;
  const float pe = (c & 1) ? cosf(ang) : sinf(ang);
  h[i] = val + pe;
}

// ---------------- fp32 -> bf16 weight conversion (4 regions) ----------------
__global__ void convert4(const float* __restrict__ s0, int n0,
                         const float* __restrict__ s1, int n1,
                         const float* __restrict__ s2, int n2,
                         const float* __restrict__ s3, int n3,
                         unsigned short* __restrict__ dst) {
  const long j = ((long)blockIdx.x * 256 + threadIdx.x) * 4;
  const float* s;
  long o = j;
  if (o < n0) s = s0;
  else { o -= n0;
    if (o < n1) s = s1;
    else { o -= n1;
      if (o < n2) s = s2;
      else { o -= n2; s = s3; } } }
  const float4 v = *(const float4*)(s + o);
  *(ushort4*)(dst + j) = make_ushort4(f2b(v.x), f2b(v.y), f2b(v.z), f2b(v.w));
}

// ---------------- LayerNorm (one block of 256 per row, 768 cols) ------------
__global__ __launch_bounds__(256)
void ln_kernel(const float* __restrict__ x, long rstride,
               const float* __restrict__ w, const float* __restrict__ bvec,
               unsigned short* __restrict__ y) {
  const int row = blockIdx.x, tid = threadIdx.x;
  const float* xr = x + (size_t)row * rstride;
  const float v0 = xr[tid], v1 = xr[tid + 256], v2 = xr[tid + 512];
  float s = v0 + v1 + v2;
  float ss = v0 * v0 + v1 * v1 + v2 * v2;
#pragma unroll
  for (int off = 32; off >= 1; off >>= 1) {
    s += __shfl_xor(s, off);
    ss += __shfl_xor(ss, off);
  }
  __shared__ float sm[8];
  const int wv = tid >> 6;
  if ((tid & 63) == 0) { sm[wv] = s; sm[wv + 4] = ss; }
  __syncthreads();
  s = sm[0] + sm[1] + sm[2] + sm[3];
  ss = sm[4] + sm[5] + sm[6] + sm[7];
  const float mu = s * (1.0f / 768.0f);
  const float var = ss * (1.0f / 768.0f) - mu * mu;
  const float rstd = rsqrtf(var + 1e-5f);
  unsigned short* yr = y + (size_t)row * CDIM;
  yr[tid]       = f2b((v0 - mu) * rstd * w[tid]       + bvec[tid]);
  yr[tid + 256] = f2b((v1 - mu) * rstd * w[tid + 256] + bvec[tid + 256]);
  yr[tid + 512] = f2b((v2 - mu) * rstd * w[tid + 512] + bvec[tid + 512]);
}

// ---------------- GEMM: C = A(M x K) * B^T(N x K), 256x256 tile, 2-phase ----
// 8 waves (2M x 4N), per-wave 128x64 output. Double-buffered 128KB LDS.
// T2 swizzle: LDS byte_in_row ^= ((row&7)<<4); applied on BOTH global_load_lds
// source (inverse-permuted col) and ds_read side (rule 21).
enum { EPI_QKV = 0, EPI_RES = 1, EPI_GELU = 2 };

template <int EPI>
__global__ __launch_bounds__(512, 2)
void gemm256(const unsigned short* __restrict__ A, const unsigned short* __restrict__ B,
             const int K,
             float* __restrict__ hres, const float* __restrict__ bias,
             unsigned short* __restrict__ obf,
             unsigned short* __restrict__ qb, unsigned short* __restrict__ kb,
             unsigned short* __restrict__ vb) {
  __shared__ unsigned short lds[65536];  // 128 KiB: A[2][256][64] | B[2][256][64]
  char* sm = (char*)lds;

  const int tid = threadIdx.x;
  const int lane = tid & 63, wv = tid >> 6;
  const int wm = wv >> 2, wn = wv & 3;
  const int ll = lane & 15, lg = lane >> 4;
  const int m0 = blockIdx.y * 256, n0 = blockIdx.x * 256;

  // staging geometry: round r (8KB) covers 64 tile rows; this thread owns
  // row srow within the round, 16B slot (lane&7), source col pre-swizzled.
  const int srow = wv * 8 + (lane >> 3);
  const int scol = (((lane & 7) ^ ((lane >> 3) & 7)) << 3);  // element index
  const unsigned short* Asrc = A + (size_t)(m0 + srow) * K + scol;
  const unsigned short* Bsrc = B + (size_t)(n0 + srow) * K + scol;
  const int sdst = wv * 1024;  // wave-uniform LDS base within a round

  f32x4 acc[8][4];
#pragma unroll
  for (int i = 0; i < 8; i++)
#pragma unroll
    for (int j = 0; j < 4; j++) acc[i][j] = (f32x4){0.f, 0.f, 0.f, 0.f};

  // prologue: stage K-tile 0 into buffer 0
#pragma unroll
  for (int r = 0; r < 4; ++r) {
    gload_lds16(Asrc + (size_t)(r * 64) * K, sm + r * 8192 + sdst);
    gload_lds16(Bsrc + (size_t)(r * 64) * K, sm + 65536 + r * 8192 + sdst);
  }
  __syncthreads();  // compiler drains vmcnt(0) here

  const int nt = K >> 6;
  int cur = 0;
  const int swz = (ll & 7) << 4;
  for (int t = 0; t < nt; ++t) {
    // issue prefetch of K-tile t+1 into the other buffer (in flight during MFMA)
    if (t + 1 < nt) {
      const int k0n = (t + 1) << 6;
      const int nb = (cur ^ 1) << 15;
#pragma unroll
      for (int r = 0; r < 4; ++r) {
        gload_lds16(Asrc + (size_t)(r * 64) * K + k0n, sm + nb + r * 8192 + sdst);
        gload_lds16(Bsrc + (size_t)(r * 64) * K + k0n, sm + 65536 + nb + r * 8192 + sdst);
      }
    }
    const char* Ab = sm + (cur << 15);
    const char* Bb = sm + 65536 + (cur << 15);
#pragma unroll
    for (int kh = 0; kh < 2; ++kh) {
      const int cb = ((kh << 6) + (lg << 4)) ^ swz;
      bf16x8 af[8], bfv[4];
#pragma unroll
      for (int i = 0; i < 8; ++i)
        af[i] = ldfrag((const unsigned short*)(Ab + (wm * 128 + i * 16 + ll) * 128 + cb));
#pragma unroll
      for (int j = 0; j < 4; ++j)
        bfv[j] = ldfrag((const unsigned short*)(Bb + (wn * 64 + j * 16 + ll) * 128 + cb));
      __builtin_amdgcn_s_setprio(1);
#pragma unroll
      for (int i = 0; i < 8; ++i)
#pragma unroll
        for (int j = 0; j < 4; ++j)
          acc[i][j] = mfma16(af[i], bfv[j], acc[i][j]);
      __builtin_amdgcn_s_setprio(0);
    }
    __syncthreads();  // drains the prefetch (vmcnt 0) + protects buffer swap
    cur ^= 1;
  }

  // epilogue
#pragma unroll
  for (int i = 0; i < 8; ++i) {
#pragma unroll
    for (int r = 0; r < 4; ++r) {
      const int m = m0 + wm * 128 + i * 16 + lg * 4 + r;
      if (m >= MTOT) continue;
      if constexpr (EPI == EPI_QKV) {
        const int b = m / 197, n = m - b * 197;
#pragma unroll
        for (int j = 0; j < 4; ++j) {
          const int e = n0 + wn * 64 + j * 16 + ll;
          const float v = acc[i][j][r];
          const int t = e / 768, rem = e - t * 768;
          const int hh = rem >> 6, d = rem & 63;
          if (t == 0)
            qb[((size_t)(b * 12 + hh) * NPAD + n) * 64 + d] = f2b(v * 0.125f);
          else if (t == 1)
            kb[((size_t)(b * 12 + hh) * NPAD + n) * 64 + d] = f2b(v);
          else
            vb[((size_t)(b * 12 + hh) * 64 + d) * NPAD + n] = f2b(v);  // V^T
        }
      } else if constexpr (EPI == EPI_RES) {
#pragma unroll
        for (int j = 0; j < 4; ++j) {
          const int c = n0 + wn * 64 + j * 16 + ll;
          const size_t idx = (size_t)m * CDIM + c;
          hres[idx] += acc[i][j][r] + bias[c];
        }
      } else {  // EPI_GELU -> bf16 store, width 3072
#pragma unroll
        for (int j = 0; j < 4; ++j) {
          const int c = n0 + wn * 64 + j * 16 + ll;
          const float tv = acc[i][j][r] + bias[c];
          const float g = 0.5f * tv * (1.0f + erff(tv * 0.7071067811865475f));
          obf[(size_t)m * FDIM + c] = f2b(g);
        }
      }
    }
  }
}

// ---------------- attention: 1 wave per (b,h,qtile of 16 rows) --------------
__global__ __launch_bounds__(64)
void attn_kernel(const unsigned short* __restrict__ qb, const unsigned short* __restrict__ kbuf,
                 const unsigned short* __restrict__ vb, unsigned short* __restrict__ o) {
  __shared__ unsigned short P[16 * 232];
  const int lane = threadIdx.x, ll = lane & 15, lg = lane >> 4;
  const int qt = blockIdx.x, bh = blockIdx.y;
  const int b = bh / 12, hh = bh - b * 12;
  const size_t base = (size_t)bh * NPAD * 64;
  const unsigned short* Q = qb + base + (size_t)qt * 16 * 64;
  const unsigned short* Kp = kbuf + base;
  const unsigned short* Vt = vb + base;  // [64][224]

  const bf16x8 qf0 = ldfrag(&Q[ll * 64 + (lg << 3)]);
  const bf16x8 qf1 = ldfrag(&Q[ll * 64 + 32 + (lg << 3)]);

  const f32x4 zero = {0.f, 0.f, 0.f, 0.f};
  f32x4 s[14];
#pragma unroll
  for (int kt = 0; kt < 14; kt++) {
    f32x4 a = zero;
    a = mfma16(qf0, ldfrag(&Kp[(kt * 16 + ll) * 64 + (lg << 3)]), a);
    a = mfma16(qf1, ldfrag(&Kp[(kt * 16 + ll) * 64 + 32 + (lg << 3)]), a);
    s[kt] = a;
  }
  float mx[4] = {-1e30f, -1e30f, -1e30f, -1e30f};
#pragma unroll
  for (int kt = 0; kt < 14; kt++) {
    const bool ok = (kt * 16 + ll) < NTOK;
#pragma unroll
    for (int r = 0; r < 4; r++) {
      const float v = ok ? s[kt][r] : -1e30f;
      s[kt][r] = v;
      mx[r] = fmaxf(mx[r], v);
    }
  }
#pragma unroll
  for (int off = 1; off < 16; off <<= 1)
#pragma unroll
    for (int r = 0; r < 4; r++) mx[r] = fmaxf(mx[r], __shfl_xor(mx[r], off));

  float sum[4] = {0.f, 0.f, 0.f, 0.f};
#pragma unroll
  for (int kt = 0; kt < 14; kt++)
#pragma unroll
    for (int r = 0; r < 4; r++) {
      const float p = __expf(s[kt][r] - mx[r]);
      sum[r] += p;
      P[(lg * 4 + r) * 232 + kt * 16 + ll] = f2b(p);
    }
#pragma unroll
  for (int off = 1; off < 16; off <<= 1)
#pragma unroll
    for (int r = 0; r < 4; r++) sum[r] += __shfl_xor(sum[r], off);

  __syncthreads();

  f32x4 oa[4] = {zero, zero, zero, zero};
#pragma unroll
  for (int ks = 0; ks < 7; ks++) {
    const bf16x8 pf = ldfrag(&P[ll * 232 + ks * 32 + (lg << 3)]);
#pragma unroll
    for (int dt = 0; dt < 4; dt++) {
      const bf16x8 vf = ldfrag(&Vt[(dt * 16 + ll) * NPAD + ks * 32 + (lg << 3)]);
      oa[dt] = mfma16(pf, vf, oa[dt]);
    }
  }
#pragma unroll
  for (int r = 0; r < 4; r++) {
    const int n = qt * 16 + lg * 4 + r;
    if (n < NTOK) {
      const float rc = 1.0f / sum[r];
      unsigned short* orow = o + ((size_t)(b * 197 + n)) * CDIM + hh * 64;
#pragma unroll
      for (int dt = 0; dt < 4; dt++) orow[dt * 16 + ll] = f2b(oa[dt][r] * rc);
    }
  }
}

// ---------------- head: cls(64x768) @ head_w^T(1000x768) + b ----------------
__global__ __launch_bounds__(64)
void head_kernel(const unsigned short* __restrict__ clsb, const unsigned short* __restrict__ hw,
                 const float* __restrict__ hb, float* __restrict__ out) {
  const int lane = threadIdx.x, ll = lane & 15, lg = lane >> 4;
  const int nt = blockIdx.x, mt = blockIdx.y;
  f32x4 acc = {0.f, 0.f, 0.f, 0.f};
  const int nrow = min(nt * 16 + ll, 999);
#pragma unroll 4
  for (int k0 = 0; k0 < 768; k0 += 32) {
    const bf16x8 a = ldfrag(&clsb[(mt * 16 + ll) * 768 + k0 + (lg << 3)]);
    const bf16x8 b = ldfrag(&hw[(size_t)nrow * 768 + k0 + (lg << 3)]);
    acc = mfma16(a, b, acc);
  }
  const int col = nt * 16 + ll;
#pragma unroll
  for (int r = 0; r < 4; r++) {
    const int row = mt * 16 + lg * 4 + r;
    if (col < 1000) out[row * 1000 + col] = acc[r] + hb[col];
  }
}

// ---------------- workspace layout ----------------
static constexpr size_t SZ_H  = (size_t)MPAD * CDIM * 4;
static constexpr size_t SZ_Y  = (size_t)MPAD * CDIM * 2;
static constexpr size_t SZ_O  = SZ_Y;
static constexpr size_t SZ_MM = (size_t)MPAD * FDIM * 2;
static constexpr size_t SZ_Q1 = (size_t)64 * 12 * NPAD * 64 * 2;
static constexpr size_t SZ_WB = (size_t)(2304 * 768 + 768 * 768 + 3072 * 768 + 768 * 3072) * 2;
static constexpr size_t OFF_H  = 0;
static constexpr size_t OFF_Y  = OFF_H + SZ_H;
static constexpr size_t OFF_O  = OFF_Y + SZ_Y;
static constexpr size_t OFF_MM = OFF_O + SZ_O;
static constexpr size_t OFF_Q  = OFF_MM + SZ_MM;
static constexpr size_t OFF_K  = OFF_Q + SZ_Q1;
static constexpr size_t OFF_V  = OFF_K + SZ_Q1;
static constexpr size_t OFF_WB = OFF_V + SZ_Q1;
static constexpr size_t OFF_WH = OFF_WB + SZ_WB;
static constexpr size_t OFF_CLS = OFF_WH + (size_t)1000 * 768 * 2;

extern "C" void kernel_launch(void* const* d_in, const int* in_sizes, int n_in,
                              void* d_out, int out_size, void* d_ws, size_t ws_size,
                              hipStream_t stream) {
  const float* x      = (const float*)d_in[0];
  const float* cls    = (const float*)d_in[1];
  const float* qkv_w  = (const float*)d_in[2];
  const float* proj_w = (const float*)d_in[3];
  const float* proj_b = (const float*)d_in[4];
  const float* ln1_w  = (const float*)d_in[5];
  const float* ln1_b  = (const float*)d_in[6];
  const float* ln2_w  = (const float*)d_in[7];
  const float* ln2_b  = (const float*)d_in[8];
  const float* fc1_w  = (const float*)d_in[9];
  const float* fc1_b  = (const float*)d_in[10];
  const float* fc2_w  = (const float*)d_in[11];
  const float* fc2_b  = (const float*)d_in[12];
  const float* norm_w = (const float*)d_in[13];
  const float* norm_b = (const float*)d_in[14];
  const float* head_w = (const float*)d_in[15];
  const float* head_b = (const float*)d_in[16];
  float* out = (float*)d_out;

  char* ws = (char*)d_ws;
  float*          h    = (float*)(ws + OFF_H);
  unsigned short* ybf  = (unsigned short*)(ws + OFF_Y);
  unsigned short* obf  = (unsigned short*)(ws + OFF_O);
  unsigned short* mmbf = (unsigned short*)(ws + OFF_MM);
  unsigned short* qbuf = (unsigned short*)(ws + OFF_Q);
  unsigned short* kbuf = (unsigned short*)(ws + OFF_K);
  unsigned short* vbuf = (unsigned short*)(ws + OFF_V);
  unsigned short* wbuf = (unsigned short*)(ws + OFF_WB);
  unsigned short* whd  = (unsigned short*)(ws + OFF_WH);
  unsigned short* clsb = (unsigned short*)(ws + OFF_CLS);

  unsigned short* wqkv = wbuf;
  unsigned short* wprj = wqkv + 2304 * 768;
  unsigned short* wfc1 = wprj + 768 * 768;
  unsigned short* wfc2 = wfc1 + 3072 * 768;

  hipMemsetAsync(ws + OFF_Q, 0, 3 * SZ_Q1, stream);

  embed_kernel<<<37824, 256, 0, stream>>>(x, cls, h);
  convert4<<<750, 256, 0, stream>>>(head_w, 768000, head_w, 0, head_w, 0, head_w, 0, whd);

  for (int d = 0; d < 12; ++d) {
    convert4<<<6912, 256, 0, stream>>>(qkv_w + (size_t)d * 2304 * 768, 2304 * 768,
                                       proj_w + (size_t)d * 768 * 768, 768 * 768,
                                       fc1_w + (size_t)d * 3072 * 768, 3072 * 768,
                                       fc2_w + (size_t)d * 768 * 3072, 768 * 3072, wbuf);
    ln_kernel<<<MTOT, 256, 0, stream>>>(h, CDIM, ln1_w + d * 768, ln1_b + d * 768, ybf);
    gemm256<EPI_QKV><<<dim3(9, 50), 512, 0, stream>>>(ybf, wqkv, 768, nullptr, nullptr,
                                                      nullptr, qbuf, kbuf, vbuf);
    attn_kernel<<<dim3(13, 768), 64, 0, stream>>>(qbuf, kbuf, vbuf, obf);
    gemm256<EPI_RES><<<dim3(3, 50), 512, 0, stream>>>(obf, wprj, 768, h, proj_b + d * 768,
                                                      nullptr, nullptr, nullptr, nullptr);
    ln_kernel<<<MTOT, 256, 0, stream>>>(h, CDIM, ln2_w + d * 768, ln2_b + d * 768, ybf);
    gemm256<EPI_GELU><<<dim3(12, 50), 512, 0, stream>>>(ybf, wfc1, 768, nullptr,
                                                        fc1_b + d * 3072, mmbf, nullptr,
                                                        nullptr, nullptr);
    gemm256<EPI_RES><<<dim3(3, 50), 512, 0, stream>>>(mmbf, wfc2, 3072, h, fc2_b + d * 768,
                                                      nullptr, nullptr, nullptr, nullptr);
  }
  ln_kernel<<<64, 256, 0, stream>>>(h, (long)197 * 768, norm_w, norm_b, clsb);
  head_kernel<<<dim3(63, 4), 64, 0, stream>>>(clsb, whd, head_b, out);
}